// Round 8
// baseline (256.053 us; speedup 1.0000x reference)
//
#include <hip/hip_runtime.h>

// ExtractTensorPatches: x (16,3,512,512) f32, window 16x16, stride 8x8, pad 0.
// out (16, 63*63, 3, 16, 16) f32.
//
// v8 == v7 == v6, third byte-identical submission. Rounds 6 & 7 both landed
// on a degraded container (fill dispatches 142-147us @ 5.4 TB/s vs 117-120us
// @ 6.5 TB/s in rounds 0-5; fill FETCH signature changed 14.5->8.0 KB), so
// the total (252.7/253.7us) is not comparable to the 227-231us LDS plateau
// measured on healthy containers. Kernel-side evidence so far: plain-store
// scatter is <142us/dispatch vs 275us for nt-scatter (round 2, healthy box)
// -> nt L2-bypass caused the 1.57x write amplification; decomposition puts
// this kernel at ~47us fast-equivalent vs ~40us write roofline and ~67us for
// the best LDS variant. This run isolates container health only.
//
// Structure (op-minimal): 1 coalesced f4 load per thread (input read exactly
// once), <=4 plain 16B stores (each output f4 written exactly once; 16B is
// the max ISA store width, so store count is at the floor; 64B/128B output
// lines are completed within one block timing-adjacently -> L2 merges).
// No LDS, no barrier, 8 VGPR -> max occupancy, 12288 blocks.

#define BB 16
#define CC 3
#define HH 512
#define WW 512
#define NH 63
#define NW 63
#define NP (NH * NW)

typedef float f4 __attribute__((ext_vector_type(4)));

__global__ __launch_bounds__(256) void scatter_patches_v8(
    const float* __restrict__ x, float* __restrict__ out) {
  unsigned int blk = blockIdx.x;
  unsigned int tid = threadIdx.x;

  // 65536 float4 per (b,c) plane; 256 blocks per plane; block covers 2 rows.
  unsigned int plane = blk >> 8;                  // b*3 + c, 0..47
  unsigned int b = plane / CC;
  unsigned int c = plane - b * CC;
  unsigned int row  = ((blk & 255u) << 1) | (tid >> 7);  // 0..511
  unsigned int col4 = tid & 127u;                 // float4 column, 0..127

  const f4* src = reinterpret_cast<const f4*>(x);
  f4 v = src[(plane << 16) + (row << 7) + col4];  // 1KB/wave, coalesced

  f4* o = reinterpret_cast<f4*>(out);
  // out f4 index = ((b*NP + ph*NW + pw)*CC + c)*64 + i*4 + s
  unsigned int base = b * (NP * CC * 64u) + c * 64u;     // b*762048 + c*64

  unsigned int ph1 = row >> 3;                    // i1 = row & 7
  unsigned int i1  = row & 7u;
  unsigned int a1 = base + ph1 * (NW * CC * 64u) + (i1 << 2);
  // ph2 = ph1-1, i2 = i1+8:  a2 = a1 - 12096 + 32
  unsigned int a2 = a1 - (NW * CC * 64u) + 32u;

  unsigned int offA = (col4 >> 1) * (CC * 64u) + (col4 & 1u);  // pwA*192 + sA
  // pwB = pwA-1, sB = sA+2:  offB = offA - 192 + 2
  unsigned int offB = offA - (CC * 64u) + 2u;

  bool r1 = row < (HH - 8u);   // ph1 <= 62
  bool r2 = row >= 8u;         // ph2 >= 0
  bool ca = col4 < 126u;       // pwA <= 62
  bool cb = col4 >= 2u;        // pwB >= 0

  if (r1 & ca) o[a1 + offA] = v;
  if (r1 & cb) o[a1 + offB] = v;
  if (r2 & ca) o[a2 + offA] = v;
  if (r2 & cb) o[a2 + offB] = v;
}

extern "C" void kernel_launch(void* const* d_in, const int* in_sizes, int n_in,
                              void* d_out, int out_size, void* d_ws, size_t ws_size,
                              hipStream_t stream) {
  const float* x = (const float*)d_in[0];
  float* out = (float*)d_out;
  scatter_patches_v8<<<dim3(BB * CC * 256), 256, 0, stream>>>(x, out);
}

// Round 9
// 241.723 us; speedup vs baseline: 1.0593x; 1.0593x over previous
//
#include <hip/hip_runtime.h>

// ExtractTensorPatches: x (16,3,512,512) f32, window 16x16, stride 8x8, pad 0.
// out (16, 63*63, 3, 16, 16) f32.
//
// v9: output-driven GATHER — the inverse of the v6-v8 scatter.
// Rationale from counters: the 6.5 TB/s fill proves a globally LINEAR write
// stream is the fastest thing this memory system does; input is L3-resident
// (round-2 FETCH 25MB < 50MB input), so scattered READS are cheap (cache-fed)
// while scattered writes must drain to DRAM. So: thread = one output f4,
// wave = one 1KB contiguous output chunk (the fill's exact store pattern,
// globally ordered), loads = 16x64B segments per wave at 2KB stride with ~4x
// temporal reuse absorbed by L1/L2/L3. XCD-bijective remap (47632 = 8*5954)
// gives each XCD a contiguous output range -> its input strip stays in its
// own L2. No LDS, no barrier, 1 load + 1 store per thread, ~16 VGPR.
// Divisions by 3/3969/63 compile to magic-muls (~15 VALU ops, negligible).

#define BB 16
#define CC 3
#define NH 63
#define NW 63
#define NP (NH * NW)                      // 3969
#define TOTAL_F4 (BB * NP * CC * 64u)     // 12,192,768 float4s
#define NBLK 47632u                       // 8 * 5954 >= TOTAL_F4/256

typedef float f4 __attribute__((ext_vector_type(4)));

__global__ __launch_bounds__(256) void gather_patches_v9(
    const float* __restrict__ x, float* __restrict__ out) {
  // Bijective XCD remap: XCD k owns contiguous output ids [k*5954,(k+1)*5954).
  unsigned blk = blockIdx.x;
  unsigned id = (blk & 7u) * (NBLK / 8u) + (blk >> 3);

  unsigned e = id * 256u + threadIdx.x;   // output f4 index
  if (e >= TOTAL_F4) return;

  unsigned q = e >> 6;                    // (b*NP + p)*CC + c
  unsigned r = e & 63u;                   // i*4 + j4 within the patch-channel
  unsigned t = q / 3u;
  unsigned c = q - t * 3u;
  unsigned b = t / 3969u;
  unsigned p = t - b * 3969u;
  unsigned ph = p / 63u;
  unsigned pw = p - ph * 63u;

  unsigned srcidx = ((b * 3u + c) << 16)            // plane base (65536 f4)
                  + ((8u * ph + (r >> 2)) << 7)     // input row (128 f4/row)
                  + 2u * pw + (r & 3u);             // input f4 column

  reinterpret_cast<f4*>(out)[e] = reinterpret_cast<const f4*>(x)[srcidx];
}

extern "C" void kernel_launch(void* const* d_in, const int* in_sizes, int n_in,
                              void* d_out, int out_size, void* d_ws, size_t ws_size,
                              hipStream_t stream) {
  const float* x = (const float*)d_in[0];
  float* out = (float*)d_out;
  gather_patches_v9<<<dim3(NBLK), 256, 0, stream>>>(x, out);
}